// Round 1
// baseline (1975.094 us; speedup 1.0000x reference)
//
#include <hip/hip_runtime.h>
#include <stdint.h>

typedef uint32_t u32;
typedef uint16_t u16;

#define HID 20
#define IN_DIM 4
#define OUT_DIM 4

// ---------- bf16 helpers ----------
__device__ __forceinline__ float bf_lo(u32 w) { return __uint_as_float(w << 16); }
__device__ __forceinline__ float bf_hi(u32 w) { return __uint_as_float(w & 0xffff0000u); }

__device__ __forceinline__ u16 f2bf(float f) {
  u32 u = __float_as_uint(f);
  u32 r = (u + 0x7fffu + ((u >> 16) & 1u)) >> 16;  // RNE; inputs finite
  return (u16)r;
}

// ---------- fast math ----------
__device__ __forceinline__ float fast_exp2(float x) {
#if __has_builtin(__builtin_amdgcn_exp2f)
  return __builtin_amdgcn_exp2f(x);
#else
  return exp2f(x);
#endif
}
__device__ __forceinline__ float fast_rcp(float x) {
#if __has_builtin(__builtin_amdgcn_rcpf)
  return __builtin_amdgcn_rcpf(x);
#else
  return 1.0f / x;
#endif
}
__device__ __forceinline__ float swish_f(float x) {
  // x * sigmoid(x) = x / (1 + exp2(-x*log2(e)))
  float e = fast_exp2(x * -1.44269504f);
  return x * fast_rcp(1.0f + e);
}

// ---------- uniform weight element access (BF: packed bf16 pairs; else f32) ----------
template <bool BF>
__device__ __forceinline__ float elem(const u32* __restrict__ p, int i) {
  if (BF) {
    u32 w = p[i >> 1];
    return (i & 1) ? bf_hi(w) : bf_lo(w);
  }
  return __uint_as_float(p[i]);
}

// t[l] = b[l] + sum_k o[k] * W[k][l]   (W row-major [HID][HID])
template <bool BF>
__device__ __forceinline__ void matvec20(float* __restrict__ t, const float* __restrict__ o,
                                         const u32* __restrict__ W, const u32* __restrict__ b) {
#pragma unroll
  for (int l = 0; l < HID; ++l) t[l] = elem<BF>(b, l);
#pragma unroll
  for (int k = 0; k < HID; ++k) {
    float ok = o[k];
#pragma unroll
    for (int l = 0; l < HID; ++l) t[l] = fmaf(ok, elem<BF>(W, k * HID + l), t[l]);
  }
}

template <bool BF>
__device__ __forceinline__ void body(
    const u32* __restrict__ xx, const u32* __restrict__ fW, const u32* __restrict__ fb,
    const u32* __restrict__ bW, const u32* __restrict__ bb,
    const u32* __restrict__ Wn1, const u32* __restrict__ bn1, const u32* __restrict__ Wl1, const u32* __restrict__ bl1,
    const u32* __restrict__ Wn2, const u32* __restrict__ bn2, const u32* __restrict__ Wl2, const u32* __restrict__ bl2,
    const u32* __restrict__ Wn3, const u32* __restrict__ bn3, const u32* __restrict__ Wl3, const u32* __restrict__ bl3,
    u32* __restrict__ out, int tid) {
  // ---- load x[tid] ----
  float xv[IN_DIM];
  if (BF) {
    uint2 d = ((const uint2*)xx)[tid];  // 4 bf16
    xv[0] = bf_lo(d.x); xv[1] = bf_hi(d.x); xv[2] = bf_lo(d.y); xv[3] = bf_hi(d.y);
  } else {
    float4 d = ((const float4*)xx)[tid];
    xv[0] = d.x; xv[1] = d.y; xv[2] = d.z; xv[3] = d.w;
  }

  // ---- front: h = x @ front_W + front_b ----
  float h[HID];
#pragma unroll
  for (int l = 0; l < HID; ++l) h[l] = elem<BF>(fb, l);
#pragma unroll
  for (int k = 0; k < IN_DIM; ++k) {
#pragma unroll
    for (int l = 0; l < HID; ++l) h[l] = fmaf(xv[k], elem<BF>(fW, k * HID + l), h[l]);
  }

  float acc[HID];
#pragma unroll
  for (int l = 0; l < HID; ++l) acc[l] = 0.f;

  // ---- three chains (rolled: one code copy for icache) ----
  for (int c = 0; c < 3; ++c) {
    const u32* Wn = (c == 0) ? Wn1 : ((c == 1) ? Wn2 : Wn3);
    const u32* bn = (c == 0) ? bn1 : ((c == 1) ? bn2 : bn3);
    const u32* Wl = (c == 0) ? Wl1 : ((c == 1) ? Wl2 : Wl3);
    const u32* bl = (c == 0) ? bl1 : ((c == 1) ? bl2 : bl3);
    const int L = (c == 0) ? 16 : ((c == 1) ? 4 : 1);

    float hc[HID];
#pragma unroll
    for (int l = 0; l < HID; ++l) hc[l] = h[l];

    for (int i = 0; i < L; ++i) {
      float o[HID], t[HID];
#pragma unroll
      for (int l = 0; l < HID; ++l) o[l] = hc[l];
      // 3 × (Linear + Swish)
      for (int j = 0; j < 3; ++j) {
        matvec20<BF>(t, o, Wn + (BF ? j * 200 : j * 400), bn + (BF ? j * 10 : j * 20));
#pragma unroll
        for (int l = 0; l < HID; ++l) o[l] = swish_f(t[l]);
      }
      // lin shortcut from block input
      matvec20<BF>(t, hc, Wl, bl);
#pragma unroll
      for (int l = 0; l < HID; ++l) hc[l] = o[l] + swish_f(t[l]);

      Wn += BF ? 600 : 1200;  // 3*HID*HID elements
      bn += BF ? 30 : 60;     // 3*HID
      Wl += BF ? 200 : 400;   // HID*HID
      bl += BF ? 10 : 20;     // HID
    }
#pragma unroll
    for (int l = 0; l < HID; ++l) acc[l] += hc[l];
  }

  // ---- back: r = acc @ back_W + back_b ----
  float r[OUT_DIM];
#pragma unroll
  for (int j = 0; j < OUT_DIM; ++j) r[j] = elem<BF>(bb, j);
#pragma unroll
  for (int k = 0; k < HID; ++k) {
#pragma unroll
    for (int j = 0; j < OUT_DIM; ++j) r[j] = fmaf(acc[k], elem<BF>(bW, k * OUT_DIM + j), r[j]);
  }

  if (BF) {
    u32 p0 = (u32)f2bf(r[0]) | ((u32)f2bf(r[1]) << 16);
    u32 p1 = (u32)f2bf(r[2]) | ((u32)f2bf(r[3]) << 16);
    ((uint2*)out)[tid] = make_uint2(p0, p1);
  } else {
    ((float4*)out)[tid] = make_float4(r[0], r[1], r[2], r[3]);
  }
}

// Detect whether x is fp32 (flag=1) or packed bf16 (flag=0).
// bf16 pairs reinterpreted as f32 give exponents ~2^±120 — implausible for N(0,1).
__global__ void detect_dtype_kernel(const u32* __restrict__ x, u32* __restrict__ flag) {
  int lane = threadIdx.x;  // 64 threads
  float f = fabsf(__uint_as_float(x[lane]));
  bool plausible = (f > 1e-6f) && (f < 1e4f);
  unsigned long long m = __ballot(plausible);
  if (lane == 0) flag[0] = (__popcll(m) >= 32) ? 1u : 0u;
}

__global__ __launch_bounds__(256) void reslinear_kernel(
    const u32* __restrict__ x, const u32* __restrict__ fW, const u32* __restrict__ fb,
    const u32* __restrict__ bW, const u32* __restrict__ bb,
    const u32* __restrict__ Wn1, const u32* __restrict__ bn1, const u32* __restrict__ Wl1, const u32* __restrict__ bl1,
    const u32* __restrict__ Wn2, const u32* __restrict__ bn2, const u32* __restrict__ Wl2, const u32* __restrict__ bl2,
    const u32* __restrict__ Wn3, const u32* __restrict__ bn3, const u32* __restrict__ Wl3, const u32* __restrict__ bl3,
    u32* __restrict__ out, const u32* __restrict__ flag, int n) {
  int tid = blockIdx.x * 256 + threadIdx.x;
  if (tid >= n) return;
  bool is_fp32 = flag ? (flag[0] != 0u) : false;
  if (is_fp32)
    body<false>(x, fW, fb, bW, bb, Wn1, bn1, Wl1, bl1, Wn2, bn2, Wl2, bl2, Wn3, bn3, Wl3, bl3, out, tid);
  else
    body<true>(x, fW, fb, bW, bb, Wn1, bn1, Wl1, bl1, Wn2, bn2, Wl2, bl2, Wn3, bn3, Wl3, bl3, out, tid);
}

extern "C" void kernel_launch(void* const* d_in, const int* in_sizes, int n_in,
                              void* d_out, int out_size, void* d_ws, size_t ws_size,
                              hipStream_t stream) {
  const u32* x   = (const u32*)d_in[0];
  const u32* fW  = (const u32*)d_in[1];
  const u32* fb  = (const u32*)d_in[2];
  const u32* bW  = (const u32*)d_in[3];
  const u32* bb  = (const u32*)d_in[4];
  const u32* Wn1 = (const u32*)d_in[5];
  const u32* bn1 = (const u32*)d_in[6];
  const u32* Wl1 = (const u32*)d_in[7];
  const u32* bl1 = (const u32*)d_in[8];
  const u32* Wn2 = (const u32*)d_in[9];
  const u32* bn2 = (const u32*)d_in[10];
  const u32* Wl2 = (const u32*)d_in[11];
  const u32* bl2 = (const u32*)d_in[12];
  const u32* Wn3 = (const u32*)d_in[13];
  const u32* bn3 = (const u32*)d_in[14];
  const u32* Wl3 = (const u32*)d_in[15];
  const u32* bl3 = (const u32*)d_in[16];

  int n = in_sizes[0] / IN_DIM;  // number of points

  u32* flag = nullptr;
  if (ws_size >= 4) {
    flag = (u32*)d_ws;
    detect_dtype_kernel<<<1, 64, 0, stream>>>(x, flag);
  }

  int grid = (n + 255) / 256;
  reslinear_kernel<<<grid, 256, 0, stream>>>(
      x, fW, fb, bW, bb, Wn1, bn1, Wl1, bl1, Wn2, bn2, Wl2, bl2,
      Wn3, bn3, Wl3, bl3, (u32*)d_out, flag, n);
}

// Round 4
// 1079.547 us; speedup vs baseline: 1.8296x; 1.8296x over previous
//
#include <hip/hip_runtime.h>
#include <stdint.h>

typedef uint32_t u32;
typedef uint16_t u16;
typedef _Float16 f16;
typedef __attribute__((ext_vector_type(8))) _Float16 f16v8;   // 8 f16 in 4 VGPRs
typedef __attribute__((ext_vector_type(16))) float f32x16;    // MFMA 32x32 accumulator

#define N_MM 86                 // front + 21 blocks * 4 + back
#define WS_NEED (N_MM * 2048)   // bytes: per matmul 2 frags * 64 lanes * 16B

// ---------- fast math ----------
__device__ __forceinline__ float fast_exp2(float x) {
#if __has_builtin(__builtin_amdgcn_exp2f)
  return __builtin_amdgcn_exp2f(x);
#else
  return exp2f(x);
#endif
}
__device__ __forceinline__ float fast_rcp(float x) {
#if __has_builtin(__builtin_amdgcn_rcpf)
  return __builtin_amdgcn_rcpf(x);
#else
  return 1.0f / x;
#endif
}
__device__ __forceinline__ float swish_f(float x) {
  float e = fast_exp2(x * -1.44269504f);
  return x * fast_rcp(1.0f + e);
}

// pack two f32 -> f16 pair in one instruction (v_cvt_pkrtz_f16_f32)
__device__ __forceinline__ u32 pkf16(float lo, float hi) {
  auto p = __builtin_amdgcn_cvt_pkrtz(lo, hi);  // [15:0]=f16(lo), [31:16]=f16(hi)
  return __builtin_bit_cast(u32, p);
}

__device__ __forceinline__ f16v8 as_f16(uint4 v) { return __builtin_bit_cast(f16v8, v); }

__device__ __forceinline__ f32x16 zero16() {
  f32x16 z = {0.f, 0.f, 0.f, 0.f, 0.f, 0.f, 0.f, 0.f,
              0.f, 0.f, 0.f, 0.f, 0.f, 0.f, 0.f, 0.f};
  return z;
}

// B fragments for one matvec: b1 covers k=0..15, b2 covers k=16..31 (k20 = bias slot = 1.0)
struct BB { uint4 b1, b2; };

// Build B fragments from C-layout values c[0..11] (rows: h=0 -> {0..3,8..11,16..19},
// h=1 -> {4..7,12..15,20..23}; rows >=20 are always 0 because A rows >=20 are zero).
__device__ __forceinline__ BB buildB(const float* c, bool hi) {
  u32 pk01 = pkf16(c[0], c[1]);
  u32 pk23 = pkf16(c[2], c[3]);
  u32 pk45 = pkf16(c[4], c[5]);
  u32 pk67 = pkf16(c[6], c[7]);
  u32 pk89 = pkf16(c[8], c[9]);
  u32 pkAB = pkf16(c[10], c[11]);
  u32 snd1 = hi ? pk01 : pk45;
  u32 snd2 = hi ? pk23 : pk67;
  u32 rcv1 = __shfl_xor(snd1, 32, 64);  // swap with lane^32
  u32 rcv2 = __shfl_xor(snd2, 32, 64);
  BB r;
  r.b1.x = hi ? rcv1 : pk01;
  r.b1.y = hi ? rcv2 : pk23;
  r.b1.z = hi ? pk45 : rcv1;
  r.b1.w = hi ? pk67 : rcv2;
  r.b2.x = hi ? 0u : pk89;
  r.b2.y = hi ? 0u : pkAB;
  r.b2.z = hi ? 0u : 0x00003C00u;  // k=20: f16(1.0) bias slot
  r.b2.w = 0u;
  return r;
}

__device__ __forceinline__ f32x16 matmul2(const uint4* __restrict__ ws4, int mm, int lane, BB b) {
  uint4 a0 = ws4[mm * 128 + lane];
  uint4 a1 = ws4[mm * 128 + 64 + lane];
  f32x16 acc = zero16();
  acc = __builtin_amdgcn_mfma_f32_32x32x16_f16(as_f16(a0), as_f16(b.b1), acc, 0, 0, 0);
  acc = __builtin_amdgcn_mfma_f32_32x32x16_f16(as_f16(a1), as_f16(b.b2), acc, 0, 0, 0);
  return acc;
}

__device__ __forceinline__ f32x16 matmul1(const uint4* __restrict__ ws4, int mm, int lane, uint4 b) {
  uint4 a0 = ws4[mm * 128 + lane];
  f32x16 acc = zero16();
  return __builtin_amdgcn_mfma_f32_32x32x16_f16(as_f16(a0), as_f16(b), acc, 0, 0, 0);
}

// ---------------- A-fragment prep: ws[mm][frag 0/1][lane][4 u32] ----------------
// A[m][k] = W[k][m] (m = out feat = lane&31, k = 16*frag + 8*(lane>>5) + 2r + h),
// bias folded at k==Kmax, zero padding elsewhere. fp32 weights -> f16 (RNE via cast).
__device__ __forceinline__ u16 f16bits(float v) {
  f16 h = (f16)v;
  return __builtin_bit_cast(u16, h);
}

__global__ void prep_kernel(
    const float* __restrict__ fW, const float* __restrict__ fb,
    const float* __restrict__ bW, const float* __restrict__ bb,
    const float* __restrict__ Wn1, const float* __restrict__ bn1,
    const float* __restrict__ Wl1, const float* __restrict__ bl1,
    const float* __restrict__ Wn2, const float* __restrict__ bn2,
    const float* __restrict__ Wl2, const float* __restrict__ bl2,
    const float* __restrict__ Wn3, const float* __restrict__ bn3,
    const float* __restrict__ Wl3, const float* __restrict__ bl3,
    u32* __restrict__ ws) {
  int mm = blockIdx.x;     // 0..85
  int lane = threadIdx.x;  // 0..63
  int m = lane & 31, g = lane >> 5;
  const float *W, *B;
  int M, Kmax, Mmax;
  if (mm == 0) { W = fW; B = fb; M = 20; Kmax = 4; Mmax = 20; }
  else if (mm == 85) { W = bW; B = bb; M = 4; Kmax = 20; Mmax = 4; }
  else {
    int idx = mm - 1, bi = idx >> 2, j = idx & 3, lb;
    const float *Wn, *bn, *Wl, *bl;
    if (bi < 16)      { Wn = Wn1; bn = bn1; Wl = Wl1; bl = bl1; lb = bi; }
    else if (bi < 20) { Wn = Wn2; bn = bn2; Wl = Wl2; bl = bl2; lb = bi - 16; }
    else              { Wn = Wn3; bn = bn3; Wl = Wl3; bl = bl3; lb = 0; }
    if (j < 3) { W = Wn + (lb * 3 + j) * 400; B = bn + (lb * 3 + j) * 20; }
    else       { W = Wl + lb * 400;           B = bl + lb * 20; }
    M = 20; Kmax = 20; Mmax = 20;
  }
  for (int f = 0; f < 2; ++f) {
    for (int r = 0; r < 4; ++r) {
      u32 v = 0;
      for (int hh = 0; hh < 2; ++hh) {
        int k = f * 16 + g * 8 + 2 * r + hh;
        u32 e = 0;
        if (m < Mmax) {
          if (k < Kmax) e = f16bits(W[k * M + m]);
          else if (k == Kmax) e = f16bits(B[m]);
        }
        v |= e << (16 * hh);
      }
      ws[mm * 512 + f * 256 + lane * 4 + r] = v;
    }
  }
}

// ---------------- main MFMA kernel: one wave = 32 points ----------------
__global__ __launch_bounds__(256) void reslinear_mfma(
    const float* __restrict__ x, const uint4* __restrict__ ws4,
    float* __restrict__ out, int ntiles) {
  int lane = threadIdx.x & 63;
  int wave = threadIdx.x >> 6;
  int tile = blockIdx.x * 4 + wave;
  if (tile >= ntiles) return;
  int n = lane & 31;
  bool hi = lane >= 32;
  int pt = tile * 32 + n;

  // ---- front: h = x @ fW + fb  (K=5 incl bias slot at k=4, single MFMA) ----
  float4 xd = ((const float4*)x)[pt];  // 4 fp32
  uint4 bfr;
  bfr.x = hi ? 0u : pkf16(xd.x, xd.y);  // k0,k1
  bfr.y = hi ? 0u : pkf16(xd.z, xd.w);  // k2,k3
  bfr.z = hi ? 0u : 0x00003C00u;        // k4 = 1.0 (bias)
  bfr.w = 0u;
  f32x16 hC = matmul1(ws4, 0, lane, bfr);
  float h[12];
#pragma unroll
  for (int l = 0; l < 12; ++l) h[l] = hC[l];

  float asum[12];
#pragma unroll
  for (int l = 0; l < 12; ++l) asum[l] = 0.f;

  const int CH_L[3] = {16, 4, 1};
  const int CH_B[3] = {0, 16, 20};

  for (int c = 0; c < 3; ++c) {
    float hc[12];
#pragma unroll
    for (int l = 0; l < 12; ++l) hc[l] = h[l];
    int L = CH_L[c];
    for (int b = 0; b < L; ++b) {
      int mm = 1 + (CH_B[c] + b) * 4;
      BB hcB = buildB(hc, hi);

      f32x16 t = matmul2(ws4, mm + 0, lane, hcB);
      float o[12];
#pragma unroll
      for (int l = 0; l < 12; ++l) o[l] = swish_f(t[l]);
      BB oB = buildB(o, hi);

      t = matmul2(ws4, mm + 1, lane, oB);
#pragma unroll
      for (int l = 0; l < 12; ++l) o[l] = swish_f(t[l]);
      oB = buildB(o, hi);

      t = matmul2(ws4, mm + 2, lane, oB);
#pragma unroll
      for (int l = 0; l < 12; ++l) o[l] = swish_f(t[l]);

      f32x16 t2 = matmul2(ws4, mm + 3, lane, hcB);  // lin shortcut from block input
#pragma unroll
      for (int l = 0; l < 12; ++l) hc[l] = o[l] + swish_f(t2[l]);
    }
#pragma unroll
    for (int l = 0; l < 12; ++l) asum[l] += hc[l];
  }

  // ---- back: out = asum @ bW + bb (rows 0..3 of C, lo lanes) ----
  BB sB = buildB(asum, hi);
  f32x16 r = matmul2(ws4, 85, lane, sB);
  if (!hi) {
    ((float4*)out)[pt] = make_float4(r[0], r[1], r[2], r[3]);
  }
}

// ---------------- fallback (ws too small / odd N): verified fp32 VALU path ----------------
__device__ __forceinline__ void matvec20f(float* __restrict__ t, const float* __restrict__ o,
                                          const float* __restrict__ W, const float* __restrict__ b) {
#pragma unroll
  for (int l = 0; l < 20; ++l) t[l] = b[l];
#pragma unroll
  for (int k = 0; k < 20; ++k) {
    float ok = o[k];
#pragma unroll
    for (int l = 0; l < 20; ++l) t[l] = fmaf(ok, W[k * 20 + l], t[l]);
  }
}
__global__ __launch_bounds__(256) void reslinear_fallback(
    const float* __restrict__ x, const float* __restrict__ fW, const float* __restrict__ fb,
    const float* __restrict__ bW, const float* __restrict__ bb,
    const float* __restrict__ Wn1, const float* __restrict__ bn1, const float* __restrict__ Wl1, const float* __restrict__ bl1,
    const float* __restrict__ Wn2, const float* __restrict__ bn2, const float* __restrict__ Wl2, const float* __restrict__ bl2,
    const float* __restrict__ Wn3, const float* __restrict__ bn3, const float* __restrict__ Wl3, const float* __restrict__ bl3,
    float* __restrict__ out, int np) {
  int tid = blockIdx.x * 256 + threadIdx.x;
  if (tid >= np) return;
  float4 d = ((const float4*)x)[tid];
  float xv[4] = {d.x, d.y, d.z, d.w};
  float h[20];
#pragma unroll
  for (int l = 0; l < 20; ++l) h[l] = fb[l];
#pragma unroll
  for (int k = 0; k < 4; ++k)
#pragma unroll
    for (int l = 0; l < 20; ++l) h[l] = fmaf(xv[k], fW[k * 20 + l], h[l]);
  float acc[20];
#pragma unroll
  for (int l = 0; l < 20; ++l) acc[l] = 0.f;
  for (int c = 0; c < 3; ++c) {
    const float* Wn = (c == 0) ? Wn1 : ((c == 1) ? Wn2 : Wn3);
    const float* bn = (c == 0) ? bn1 : ((c == 1) ? bn2 : bn3);
    const float* Wl = (c == 0) ? Wl1 : ((c == 1) ? Wl2 : Wl3);
    const float* bl = (c == 0) ? bl1 : ((c == 1) ? bl2 : bl3);
    const int L = (c == 0) ? 16 : ((c == 1) ? 4 : 1);
    float hc[20];
#pragma unroll
    for (int l = 0; l < 20; ++l) hc[l] = h[l];
    for (int i = 0; i < L; ++i) {
      float o[20], t[20];
#pragma unroll
      for (int l = 0; l < 20; ++l) o[l] = hc[l];
      for (int j = 0; j < 3; ++j) {
        matvec20f(t, o, Wn + j * 400, bn + j * 20);
#pragma unroll
        for (int l = 0; l < 20; ++l) o[l] = swish_f(t[l]);
      }
      matvec20f(t, hc, Wl, bl);
#pragma unroll
      for (int l = 0; l < 20; ++l) hc[l] = o[l] + swish_f(t[l]);
      Wn += 1200; bn += 60; Wl += 400; bl += 20;
    }
#pragma unroll
    for (int l = 0; l < 20; ++l) acc[l] += hc[l];
  }
  float r[4];
#pragma unroll
  for (int j = 0; j < 4; ++j) r[j] = bb[j];
#pragma unroll
  for (int k = 0; k < 20; ++k)
#pragma unroll
    for (int j = 0; j < 4; ++j) r[j] = fmaf(acc[k], bW[k * 4 + j], r[j]);
  ((float4*)out)[tid] = make_float4(r[0], r[1], r[2], r[3]);
}

extern "C" void kernel_launch(void* const* d_in, const int* in_sizes, int n_in,
                              void* d_out, int out_size, void* d_ws, size_t ws_size,
                              hipStream_t stream) {
  int np = in_sizes[0] / 4;  // number of points

  if (ws_size >= (size_t)WS_NEED && (np % 32) == 0) {
    prep_kernel<<<N_MM, 64, 0, stream>>>(
        (const float*)d_in[1], (const float*)d_in[2], (const float*)d_in[3], (const float*)d_in[4],
        (const float*)d_in[5], (const float*)d_in[6], (const float*)d_in[7], (const float*)d_in[8],
        (const float*)d_in[9], (const float*)d_in[10], (const float*)d_in[11], (const float*)d_in[12],
        (const float*)d_in[13], (const float*)d_in[14], (const float*)d_in[15], (const float*)d_in[16],
        (u32*)d_ws);
    int ntiles = np / 32;
    int blocks = (ntiles + 3) / 4;
    reslinear_mfma<<<blocks, 256, 0, stream>>>(
        (const float*)d_in[0], (const uint4*)d_ws, (float*)d_out, ntiles);
  } else {
    reslinear_fallback<<<(np + 255) / 256, 256, 0, stream>>>(
        (const float*)d_in[0], (const float*)d_in[1], (const float*)d_in[2], (const float*)d_in[3],
        (const float*)d_in[4], (const float*)d_in[5], (const float*)d_in[6], (const float*)d_in[7],
        (const float*)d_in[8], (const float*)d_in[9], (const float*)d_in[10], (const float*)d_in[11],
        (const float*)d_in[12], (const float*)d_in[13], (const float*)d_in[14], (const float*)d_in[15],
        (const float*)d_in[16], (float*)d_out, np);
  }
}

// Round 5
// 946.571 us; speedup vs baseline: 2.0866x; 1.1405x over previous
//
#include <hip/hip_runtime.h>
#include <stdint.h>

typedef uint32_t u32;
typedef uint16_t u16;
typedef _Float16 f16;
typedef __attribute__((ext_vector_type(8))) _Float16 f16v8;   // 8 f16 in 4 VGPRs
typedef __attribute__((ext_vector_type(16))) float f32x16;    // MFMA 32x32 accumulator

#define N_MM 86                 // front + 21 blocks * 4 + back
#define WS_NEED (N_MM * 2048)   // bytes: per matmul 2 frags * 64 lanes * 16B
#define LOG2E 1.44269504f
#define LN2 0.6931471806f

// ---------- fast math ----------
__device__ __forceinline__ float fast_exp2(float x) {
#if __has_builtin(__builtin_amdgcn_exp2f)
  return __builtin_amdgcn_exp2f(x);
#else
  return exp2f(x);
#endif
}
__device__ __forceinline__ float fast_rcp(float x) {
#if __has_builtin(__builtin_amdgcn_rcpf)
  return __builtin_amdgcn_rcpf(x);
#else
  return 1.0f / x;
#endif
}
// scaled-domain swish: input u = log2e * t, output = log2e * (t * sigmoid(t))
__device__ __forceinline__ float swish_u(float u) {
  return u * fast_rcp(1.0f + fast_exp2(-u));
}

// pack two f32 -> f16 pair in one instruction (v_cvt_pkrtz_f16_f32)
__device__ __forceinline__ u32 pkf16(float lo, float hi) {
  auto p = __builtin_amdgcn_cvt_pkrtz(lo, hi);  // [15:0]=f16(lo), [31:16]=f16(hi)
  return __builtin_bit_cast(u32, p);
}

__device__ __forceinline__ f16v8 as_f16(uint4 v) { return __builtin_bit_cast(f16v8, v); }

__device__ __forceinline__ f32x16 zero16() {
  f32x16 z = {0.f, 0.f, 0.f, 0.f, 0.f, 0.f, 0.f, 0.f,
              0.f, 0.f, 0.f, 0.f, 0.f, 0.f, 0.f, 0.f};
  return z;
}

// B fragments: with the permuted A logical-k mapping, each lane's B values are
// exactly its own C registers c0..c11 in order. No shuffles, no cndmasks.
// (g=1 lanes' c8..c11 are C rows 20..23 == 0; A-side zero padding kills any
// slot whose B value is "garbage".)
struct BB { uint4 b1, b2; };

__device__ __forceinline__ BB buildB(const float* c) {
  BB r;
  r.b1.x = pkf16(c[0], c[1]);
  r.b1.y = pkf16(c[2], c[3]);
  r.b1.z = pkf16(c[4], c[5]);
  r.b1.w = pkf16(c[6], c[7]);
  r.b2.x = pkf16(c[8], c[9]);
  r.b2.y = pkf16(c[10], c[11]);
  r.b2.z = 0x00003C00u;  // bias slot (s=4 of frag2, g=0): f16(1.0)
  r.b2.w = 0u;
  return r;
}

__device__ __forceinline__ f32x16 matmul2(const uint4* __restrict__ ws4, int mm, int lane, BB b) {
  uint4 a0 = ws4[mm * 128 + lane];
  uint4 a1 = ws4[mm * 128 + 64 + lane];
  f32x16 acc = zero16();
  acc = __builtin_amdgcn_mfma_f32_32x32x16_f16(as_f16(a0), as_f16(b.b1), acc, 0, 0, 0);
  acc = __builtin_amdgcn_mfma_f32_32x32x16_f16(as_f16(a1), as_f16(b.b2), acc, 0, 0, 0);
  return acc;
}

__device__ __forceinline__ f32x16 matmul1(const uint4* __restrict__ ws4, int mm, int lane, uint4 b) {
  uint4 a0 = ws4[mm * 128 + lane];
  f32x16 acc = zero16();
  return __builtin_amdgcn_mfma_f32_32x32x16_f16(as_f16(a0), as_f16(b), acc, 0, 0, 0);
}

// ---------------- A-fragment prep: ws[mm][frag 0/1][lane][4 u32] ----------------
// Permuted logical-k mapping (s = 2r+hh is the in-lane slot):
//   blocks/back: f=0: k = 4g + s + (s>=4 ? 4 : 0)      (g=0: 0-3,8-11; g=1: 4-7,12-15)
//                f=1: g=0: s<4 -> 16+s, s==4 -> BIAS; else PAD
//   front:       f=0: g=0: s<4 -> k=s, s==4 -> BIAS; else PAD (single-MFMA matvec)
// Scaled domain: bias *= log2e; front W *= log2e; back W *= ln2, back bias *= 1.
__device__ __forceinline__ u16 f16bits(float v) {
  f16 h = (f16)v;
  return __builtin_bit_cast(u16, h);
}

__global__ void prep_kernel(
    const float* __restrict__ fW, const float* __restrict__ fb,
    const float* __restrict__ bW, const float* __restrict__ bb,
    const float* __restrict__ Wn1, const float* __restrict__ bn1,
    const float* __restrict__ Wl1, const float* __restrict__ bl1,
    const float* __restrict__ Wn2, const float* __restrict__ bn2,
    const float* __restrict__ Wl2, const float* __restrict__ bl2,
    const float* __restrict__ Wn3, const float* __restrict__ bn3,
    const float* __restrict__ Wl3, const float* __restrict__ bl3,
    u32* __restrict__ ws) {
  int mm = blockIdx.x;     // 0..85
  int lane = threadIdx.x;  // 0..63
  int m = lane & 31, g = lane >> 5;
  const float *W, *B;
  int M, Kmax, Mmax;
  float sW, sB;
  bool front = (mm == 0);
  if (mm == 0) { W = fW; B = fb; M = 20; Kmax = 4; Mmax = 20; sW = LOG2E; sB = LOG2E; }
  else if (mm == 85) { W = bW; B = bb; M = 4; Kmax = 20; Mmax = 4; sW = LN2; sB = 1.0f; }
  else {
    int idx = mm - 1, bi = idx >> 2, j = idx & 3, lb;
    const float *Wn, *bn, *Wl, *bl;
    if (bi < 16)      { Wn = Wn1; bn = bn1; Wl = Wl1; bl = bl1; lb = bi; }
    else if (bi < 20) { Wn = Wn2; bn = bn2; Wl = Wl2; bl = bl2; lb = bi - 16; }
    else              { Wn = Wn3; bn = bn3; Wl = Wl3; bl = bl3; lb = 0; }
    if (j < 3) { W = Wn + (lb * 3 + j) * 400; B = bn + (lb * 3 + j) * 20; }
    else       { W = Wl + lb * 400;           B = bl + lb * 20; }
    M = 20; Kmax = 20; Mmax = 20; sW = 1.0f; sB = LOG2E;
  }
  for (int f = 0; f < 2; ++f) {
    for (int r = 0; r < 4; ++r) {
      u32 v = 0;
      for (int hh = 0; hh < 2; ++hh) {
        int s = 2 * r + hh;
        int k = -1;
        bool bias = false;
        if (front) {
          if (f == 0 && g == 0) {
            if (s < 4) k = s;
            else if (s == 4) bias = true;
          }
        } else {
          if (f == 0) k = 4 * g + s + (s >= 4 ? 4 : 0);
          else if (g == 0) {
            if (s < 4) k = 16 + s;
            else if (s == 4) bias = true;
          }
        }
        u32 e = 0;
        if (m < Mmax) {
          if (bias) e = f16bits(sB * B[m]);
          else if (k >= 0 && k < Kmax) e = f16bits(sW * W[k * M + m]);
        }
        v |= e << (16 * hh);
      }
      ws[mm * 512 + f * 256 + lane * 4 + r] = v;
    }
  }
}

// ---------------- main MFMA kernel: one wave = 32 points ----------------
__global__ __launch_bounds__(256) void reslinear_mfma(
    const float* __restrict__ x, const uint4* __restrict__ ws4,
    float* __restrict__ out, int ntiles) {
  int lane = threadIdx.x & 63;
  int wave = threadIdx.x >> 6;
  int tile = blockIdx.x * 4 + wave;
  if (tile >= ntiles) return;
  int n = lane & 31;
  bool hi = lane >= 32;
  int pt = tile * 32 + n;

  // ---- front: h' = log2e*(x @ fW + fb)  (K=5 incl bias at s=4, single MFMA) ----
  float4 xd = ((const float4*)x)[pt];  // 4 fp32
  uint4 bfr;
  bfr.x = pkf16(xd.x, xd.y);  // s0,s1 (g=1 lanes: killed by A-side zeros)
  bfr.y = pkf16(xd.z, xd.w);  // s2,s3
  bfr.z = 0x00003C00u;        // s4 = 1.0 (bias)
  bfr.w = 0u;
  f32x16 hC = matmul1(ws4, 0, lane, bfr);
  float h[12];
#pragma unroll
  for (int l = 0; l < 12; ++l) h[l] = hC[l];

  float asum[12];
#pragma unroll
  for (int l = 0; l < 12; ++l) asum[l] = 0.f;

  const int CH_L[3] = {16, 4, 1};
  const int CH_B[3] = {0, 16, 20};

  for (int c = 0; c < 3; ++c) {
    float hc[12];
#pragma unroll
    for (int l = 0; l < 12; ++l) hc[l] = h[l];
    int L = CH_L[c];
    for (int b = 0; b < L; ++b) {
      int mm = 1 + (CH_B[c] + b) * 4;
      BB hcB = buildB(hc);

      f32x16 t = matmul2(ws4, mm + 0, lane, hcB);
      float o[12];
#pragma unroll
      for (int l = 0; l < 12; ++l) o[l] = swish_u(t[l]);
      BB oB = buildB(o);

      t = matmul2(ws4, mm + 1, lane, oB);
#pragma unroll
      for (int l = 0; l < 12; ++l) o[l] = swish_u(t[l]);
      oB = buildB(o);

      t = matmul2(ws4, mm + 2, lane, oB);
#pragma unroll
      for (int l = 0; l < 12; ++l) o[l] = swish_u(t[l]);

      f32x16 t2 = matmul2(ws4, mm + 3, lane, hcB);  // lin shortcut from block input
#pragma unroll
      for (int l = 0; l < 12; ++l) hc[l] = o[l] + swish_u(t2[l]);
    }
#pragma unroll
    for (int l = 0; l < 12; ++l) asum[l] += hc[l];
  }

  // ---- back: out = asum' @ (ln2*bW) + bb (rows 0..3 of C, lo lanes) ----
  BB sB = buildB(asum);
  f32x16 r = matmul2(ws4, 85, lane, sB);
  if (!hi) {
    ((float4*)out)[pt] = make_float4(r[0], r[1], r[2], r[3]);
  }
}

// ---------------- fallback (ws too small / odd N): verified fp32 VALU path ----------------
__device__ __forceinline__ float swish_f(float x) {
  float e = fast_exp2(x * -LOG2E);
  return x * fast_rcp(1.0f + e);
}
__device__ __forceinline__ void matvec20f(float* __restrict__ t, const float* __restrict__ o,
                                          const float* __restrict__ W, const float* __restrict__ b) {
#pragma unroll
  for (int l = 0; l < 20; ++l) t[l] = b[l];
#pragma unroll
  for (int k = 0; k < 20; ++k) {
    float ok = o[k];
#pragma unroll
    for (int l = 0; l < 20; ++l) t[l] = fmaf(ok, W[k * 20 + l], t[l]);
  }
}
__global__ __launch_bounds__(256) void reslinear_fallback(
    const float* __restrict__ x, const float* __restrict__ fW, const float* __restrict__ fb,
    const float* __restrict__ bW, const float* __restrict__ bb,
    const float* __restrict__ Wn1, const float* __restrict__ bn1, const float* __restrict__ Wl1, const float* __restrict__ bl1,
    const float* __restrict__ Wn2, const float* __restrict__ bn2, const float* __restrict__ Wl2, const float* __restrict__ bl2,
    const float* __restrict__ Wn3, const float* __restrict__ bn3, const float* __restrict__ Wl3, const float* __restrict__ bl3,
    float* __restrict__ out, int np) {
  int tid = blockIdx.x * 256 + threadIdx.x;
  if (tid >= np) return;
  float4 d = ((const float4*)x)[tid];
  float xv[4] = {d.x, d.y, d.z, d.w};
  float h[20];
#pragma unroll
  for (int l = 0; l < 20; ++l) h[l] = fb[l];
#pragma unroll
  for (int k = 0; k < 4; ++k)
#pragma unroll
    for (int l = 0; l < 20; ++l) h[l] = fmaf(xv[k], fW[k * 20 + l], h[l]);
  float acc[20];
#pragma unroll
  for (int l = 0; l < 20; ++l) acc[l] = 0.f;
  for (int c = 0; c < 3; ++c) {
    const float* Wn = (c == 0) ? Wn1 : ((c == 1) ? Wn2 : Wn3);
    const float* bn = (c == 0) ? bn1 : ((c == 1) ? bn2 : bn3);
    const float* Wl = (c == 0) ? Wl1 : ((c == 1) ? Wl2 : Wl3);
    const float* bl = (c == 0) ? bl1 : ((c == 1) ? bl2 : bl3);
    const int L = (c == 0) ? 16 : ((c == 1) ? 4 : 1);
    float hc[20];
#pragma unroll
    for (int l = 0; l < 20; ++l) hc[l] = h[l];
    for (int i = 0; i < L; ++i) {
      float o[20], t[20];
#pragma unroll
      for (int l = 0; l < 20; ++l) o[l] = hc[l];
      for (int j = 0; j < 3; ++j) {
        matvec20f(t, o, Wn + j * 400, bn + j * 20);
#pragma unroll
        for (int l = 0; l < 20; ++l) o[l] = swish_f(t[l]);
      }
      matvec20f(t, hc, Wl, bl);
#pragma unroll
      for (int l = 0; l < 20; ++l) hc[l] = o[l] + swish_f(t[l]);
      Wn += 1200; bn += 60; Wl += 400; bl += 20;
    }
#pragma unroll
    for (int l = 0; l < 20; ++l) acc[l] += hc[l];
  }
  float r[4];
#pragma unroll
  for (int j = 0; j < 4; ++j) r[j] = bb[j];
#pragma unroll
  for (int k = 0; k < 20; ++k)
#pragma unroll
    for (int j = 0; j < 4; ++j) r[j] = fmaf(acc[k], bW[k * 4 + j], r[j]);
  ((float4*)out)[tid] = make_float4(r[0], r[1], r[2], r[3]);
}

extern "C" void kernel_launch(void* const* d_in, const int* in_sizes, int n_in,
                              void* d_out, int out_size, void* d_ws, size_t ws_size,
                              hipStream_t stream) {
  int np = in_sizes[0] / 4;  // number of points

  if (ws_size >= (size_t)WS_NEED && (np % 32) == 0) {
    prep_kernel<<<N_MM, 64, 0, stream>>>(
        (const float*)d_in[1], (const float*)d_in[2], (const float*)d_in[3], (const float*)d_in[4],
        (const float*)d_in[5], (const float*)d_in[6], (const float*)d_in[7], (const float*)d_in[8],
        (const float*)d_in[9], (const float*)d_in[10], (const float*)d_in[11], (const float*)d_in[12],
        (const float*)d_in[13], (const float*)d_in[14], (const float*)d_in[15], (const float*)d_in[16],
        (u32*)d_ws);
    int ntiles = np / 32;
    int blocks = (ntiles + 3) / 4;
    reslinear_mfma<<<blocks, 256, 0, stream>>>(
        (const float*)d_in[0], (const uint4*)d_ws, (float*)d_out, ntiles);
  } else {
    reslinear_fallback<<<(np + 255) / 256, 256, 0, stream>>>(
        (const float*)d_in[0], (const float*)d_in[1], (const float*)d_in[2], (const float*)d_in[3],
        (const float*)d_in[4], (const float*)d_in[5], (const float*)d_in[6], (const float*)d_in[7],
        (const float*)d_in[8], (const float*)d_in[9], (const float*)d_in[10], (const float*)d_in[11],
        (const float*)d_in[12], (const float*)d_in[13], (const float*)d_in[14], (const float*)d_in[15],
        (const float*)d_in[16], (float*)d_out, np);
  }
}

// Round 6
// 742.144 us; speedup vs baseline: 2.6613x; 1.2755x over previous
//
#include <hip/hip_runtime.h>
#include <stdint.h>

typedef uint32_t u32;
typedef uint16_t u16;
typedef _Float16 f16;
typedef __attribute__((ext_vector_type(2))) _Float16 h2;
typedef __attribute__((ext_vector_type(8))) _Float16 f16v8;   // 8 f16 in 4 VGPRs
typedef __attribute__((ext_vector_type(16))) float f32x16;    // MFMA 32x32 accumulator

#define N_MM 86                 // front + 21 blocks * 4 + back
#define WS_NEED (N_MM * 2048)   // bytes: per matmul 2 frags * 64 lanes * 16B
#define LOG2E 1.44269504f
#define BETA (LOG2E / 4.5f)     // activation storage scale: m = BETA * v
#define INVBETA (4.5f / LOG2E)

// Packed-f16 coefficients for q(s), s=w^2, w=u/4.5: sigma2(u) ~= clamp01(0.5 + w*q(s)).
// Chebyshev interpolation of (sigma2-0.5)/w on u in [-4.5,4.5]; max err ~1.5e-4.
#define D0 0x3A3D3A3Du  //  0.77978
#define D1 0xB8FDB8FDu  // -0.62354
#define D2 0x38483848u  //  0.53516
#define D3 0xB539B539u  // -0.32642
#define D4 0x2DF12DF1u  //  0.092834
#define HALF2 0x38003800u
#define ONE2 0x3C003C00u
#define ONEF16 0x00003C00u

// ---------- packed helpers ----------
__device__ __forceinline__ u32 pkf16(float lo, float hi) {
  auto p = __builtin_amdgcn_cvt_pkrtz(lo, hi);  // v_cvt_pkrtz_f16_f32
  return __builtin_bit_cast(u32, p);
}
__device__ __forceinline__ h2 uph(u32 v) { return __builtin_bit_cast(h2, v); }
__device__ __forceinline__ u32 phu(h2 v) { return __builtin_bit_cast(u32, v); }
__device__ __forceinline__ u32 pkadd(u32 a, u32 b) { return phu(uph(a) + uph(b)); }

__device__ __forceinline__ f16v8 as_f16(uint4 v) { return __builtin_bit_cast(f16v8, v); }

__device__ __forceinline__ f32x16 zero16() {
  f32x16 z = {0.f, 0.f, 0.f, 0.f, 0.f, 0.f, 0.f, 0.f,
              0.f, 0.f, 0.f, 0.f, 0.f, 0.f, 0.f, 0.f};
  return z;
}

// packed polynomial swish: in = packed pre-act c (w-domain), out = packed m = c * sigma
__device__ __forceinline__ void swish6(const f32x16& t, u32* o) {
  const h2 d0 = uph(D0), d1 = uph(D1), d2 = uph(D2), d3 = uph(D3), d4 = uph(D4);
  const h2 hf = uph(HALF2), zr = uph(0u), on = uph(ONE2);
#pragma unroll
  for (int i = 0; i < 6; ++i) {
    h2 c = uph(pkf16(t[2 * i], t[2 * i + 1]));
    h2 s = c * c;
    h2 p = __builtin_elementwise_fma(d4, s, d3);
    p = __builtin_elementwise_fma(p, s, d2);
    p = __builtin_elementwise_fma(p, s, d1);
    p = __builtin_elementwise_fma(p, s, d0);
    h2 sg = __builtin_elementwise_fma(c, p, hf);
    sg = __builtin_elementwise_max(sg, zr);
    sg = __builtin_elementwise_min(sg, on);
    o[i] = phu(c * sg);
  }
}

// matvec: activations a6[0..5] (packed m-domain) + bias slot; two MFMAs
__device__ __forceinline__ f32x16 matmul2(const uint4* __restrict__ ws4, int mm, int lane,
                                          const u32* a6, const f32x16& Z) {
  uint4 a0 = ws4[mm * 128 + lane];
  uint4 a1 = ws4[mm * 128 + 64 + lane];
  uint4 b1, b2;
  b1.x = a6[0]; b1.y = a6[1]; b1.z = a6[2]; b1.w = a6[3];
  b2.x = a6[4]; b2.y = a6[5]; b2.z = ONEF16; b2.w = 0u;
  f32x16 acc = __builtin_amdgcn_mfma_f32_32x32x16_f16(as_f16(a0), as_f16(b1), Z, 0, 0, 0);
  acc = __builtin_amdgcn_mfma_f32_32x32x16_f16(as_f16(a1), as_f16(b2), acc, 0, 0, 0);
  return acc;
}

__device__ __forceinline__ f32x16 matmul1(const uint4* __restrict__ ws4, int mm, int lane,
                                          uint4 b, const f32x16& Z) {
  uint4 a0 = ws4[mm * 128 + lane];
  return __builtin_amdgcn_mfma_f32_32x32x16_f16(as_f16(a0), as_f16(b), Z, 0, 0, 0);
}

// ---------------- A-fragment prep: ws[mm][frag 0/1][lane][4 u32] ----------------
// Permuted logical-k mapping (s = 2r+hh is the in-lane slot):
//   blocks/back: f=0: k = 4g + s + (s>=4 ? 4 : 0)      (g=0: 0-3,8-11; g=1: 4-7,12-15)
//                f=1: g=0: s<4 -> 16+s, s==4 -> BIAS; else PAD
//   front:       f=0: g=0: s<4 -> k=s, s==4 -> BIAS; else PAD (single-MFMA matvec)
// m-domain scaling: hidden W x1, hidden b xBETA; front W,b xBETA; back W xINVBETA, b x1.
__device__ __forceinline__ u16 f16bits(float v) {
  f16 h = (f16)v;
  return __builtin_bit_cast(u16, h);
}

__global__ void prep_kernel(
    const float* __restrict__ fW, const float* __restrict__ fb,
    const float* __restrict__ bW, const float* __restrict__ bb,
    const float* __restrict__ Wn1, const float* __restrict__ bn1,
    const float* __restrict__ Wl1, const float* __restrict__ bl1,
    const float* __restrict__ Wn2, const float* __restrict__ bn2,
    const float* __restrict__ Wl2, const float* __restrict__ bl2,
    const float* __restrict__ Wn3, const float* __restrict__ bn3,
    const float* __restrict__ Wl3, const float* __restrict__ bl3,
    u32* __restrict__ ws) {
  int mm = blockIdx.x;     // 0..85
  int lane = threadIdx.x;  // 0..63
  int m = lane & 31, g = lane >> 5;
  const float *W, *B;
  int M, Kmax, Mmax;
  float sW, sB;
  bool front = (mm == 0);
  if (mm == 0) { W = fW; B = fb; M = 20; Kmax = 4; Mmax = 20; sW = BETA; sB = BETA; }
  else if (mm == 85) { W = bW; B = bb; M = 4; Kmax = 20; Mmax = 4; sW = INVBETA; sB = 1.0f; }
  else {
    int idx = mm - 1, bi = idx >> 2, j = idx & 3, lb;
    const float *Wn, *bn, *Wl, *bl;
    if (bi < 16)      { Wn = Wn1; bn = bn1; Wl = Wl1; bl = bl1; lb = bi; }
    else if (bi < 20) { Wn = Wn2; bn = bn2; Wl = Wl2; bl = bl2; lb = bi - 16; }
    else              { Wn = Wn3; bn = bn3; Wl = Wl3; bl = bl3; lb = 0; }
    if (j < 3) { W = Wn + (lb * 3 + j) * 400; B = bn + (lb * 3 + j) * 20; }
    else       { W = Wl + lb * 400;           B = bl + lb * 20; }
    M = 20; Kmax = 20; Mmax = 20; sW = 1.0f; sB = BETA;
  }
  for (int f = 0; f < 2; ++f) {
    for (int r = 0; r < 4; ++r) {
      u32 v = 0;
      for (int hh = 0; hh < 2; ++hh) {
        int s = 2 * r + hh;
        int k = -1;
        bool bias = false;
        if (front) {
          if (f == 0 && g == 0) {
            if (s < 4) k = s;
            else if (s == 4) bias = true;
          }
        } else {
          if (f == 0) k = 4 * g + s + (s >= 4 ? 4 : 0);
          else if (g == 0) {
            if (s < 4) k = 16 + s;
            else if (s == 4) bias = true;
          }
        }
        u32 e = 0;
        if (m < Mmax) {
          if (bias) e = f16bits(sB * B[m]);
          else if (k >= 0 && k < Kmax) e = f16bits(sW * W[k * M + m]);
        }
        v |= e << (16 * hh);
      }
      ws[mm * 512 + f * 256 + lane * 4 + r] = v;
    }
  }
}

// ---------------- main MFMA kernel: one wave = 32 points ----------------
__global__ __launch_bounds__(256) void reslinear_mfma(
    const float* __restrict__ x, const uint4* __restrict__ ws4,
    float* __restrict__ out, int ntiles) {
  int lane = threadIdx.x & 63;
  int wave = threadIdx.x >> 6;
  int tile = blockIdx.x * 4 + wave;
  if (tile >= ntiles) return;
  int n = lane & 31;
  bool hi = lane >= 32;
  int pt = tile * 32 + n;

  const f32x16 Z = zero16();  // persistent zero accumulator bank

  // ---- front: c = BETA*(x @ fW + fb); no activation, feeds blocks directly ----
  float4 xd = ((const float4*)x)[pt];
  uint4 bfr;
  bfr.x = pkf16(xd.x, xd.y);
  bfr.y = pkf16(xd.z, xd.w);
  bfr.z = ONEF16;
  bfr.w = 0u;
  f32x16 hC = matmul1(ws4, 0, lane, bfr, Z);
  u32 h[6];
#pragma unroll
  for (int i = 0; i < 6; ++i) h[i] = pkf16(hC[2 * i], hC[2 * i + 1]);

  u32 asum[6];
#pragma unroll
  for (int i = 0; i < 6; ++i) asum[i] = 0u;  // packed f16 +0.0

  const int CH_L[3] = {16, 4, 1};
  const int CH_B[3] = {0, 16, 20};

  for (int c = 0; c < 3; ++c) {
    u32 cur[6];
#pragma unroll
    for (int i = 0; i < 6; ++i) cur[i] = h[i];
    int L = CH_L[c];
    for (int b = 0; b < L; ++b) {
      int mm = 1 + (CH_B[c] + b) * 4;
      u32 o[6], o2[6];
      f32x16 t = matmul2(ws4, mm + 0, lane, cur, Z);
      swish6(t, o);
      t = matmul2(ws4, mm + 1, lane, o, Z);
      swish6(t, o);
      t = matmul2(ws4, mm + 2, lane, o, Z);
      swish6(t, o);
      t = matmul2(ws4, mm + 3, lane, cur, Z);  // lin shortcut from block input
      swish6(t, o2);
#pragma unroll
      for (int i = 0; i < 6; ++i) cur[i] = pkadd(o[i], o2[i]);
    }
#pragma unroll
    for (int i = 0; i < 6; ++i) asum[i] = pkadd(asum[i], cur[i]);
  }

  // ---- back: out = (bW/BETA) @ asum + bb (rows 0..3 of C, lo lanes) ----
  f32x16 r = matmul2(ws4, 85, lane, asum, Z);
  if (!hi) {
    ((float4*)out)[pt] = make_float4(r[0], r[1], r[2], r[3]);
  }
}

// ---------------- fallback (ws too small / odd N): verified fp32 VALU path ----------------
__device__ __forceinline__ float fast_exp2(float x) {
#if __has_builtin(__builtin_amdgcn_exp2f)
  return __builtin_amdgcn_exp2f(x);
#else
  return exp2f(x);
#endif
}
__device__ __forceinline__ float fast_rcp(float x) {
#if __has_builtin(__builtin_amdgcn_rcpf)
  return __builtin_amdgcn_rcpf(x);
#else
  return 1.0f / x;
#endif
}
__device__ __forceinline__ float swish_f(float x) {
  float e = fast_exp2(x * -LOG2E);
  return x * fast_rcp(1.0f + e);
}
__device__ __forceinline__ void matvec20f(float* __restrict__ t, const float* __restrict__ o,
                                          const float* __restrict__ W, const float* __restrict__ b) {
#pragma unroll
  for (int l = 0; l < 20; ++l) t[l] = b[l];
#pragma unroll
  for (int k = 0; k < 20; ++k) {
    float ok = o[k];
#pragma unroll
    for (int l = 0; l < 20; ++l) t[l] = fmaf(ok, W[k * 20 + l], t[l]);
  }
}
__global__ __launch_bounds__(256) void reslinear_fallback(
    const float* __restrict__ x, const float* __restrict__ fW, const float* __restrict__ fb,
    const float* __restrict__ bW, const float* __restrict__ bb,
    const float* __restrict__ Wn1, const float* __restrict__ bn1, const float* __restrict__ Wl1, const float* __restrict__ bl1,
    const float* __restrict__ Wn2, const float* __restrict__ bn2, const float* __restrict__ Wl2, const float* __restrict__ bl2,
    const float* __restrict__ Wn3, const float* __restrict__ bn3, const float* __restrict__ Wl3, const float* __restrict__ bl3,
    float* __restrict__ out, int np) {
  int tid = blockIdx.x * 256 + threadIdx.x;
  if (tid >= np) return;
  float4 d = ((const float4*)x)[tid];
  float xv[4] = {d.x, d.y, d.z, d.w};
  float h[20];
#pragma unroll
  for (int l = 0; l < 20; ++l) h[l] = fb[l];
#pragma unroll
  for (int k = 0; k < 4; ++k)
#pragma unroll
    for (int l = 0; l < 20; ++l) h[l] = fmaf(xv[k], fW[k * 20 + l], h[l]);
  float acc[20];
#pragma unroll
  for (int l = 0; l < 20; ++l) acc[l] = 0.f;
  for (int c = 0; c < 3; ++c) {
    const float* Wn = (c == 0) ? Wn1 : ((c == 1) ? Wn2 : Wn3);
    const float* bn = (c == 0) ? bn1 : ((c == 1) ? bn2 : bn3);
    const float* Wl = (c == 0) ? Wl1 : ((c == 1) ? Wl2 : Wl3);
    const float* bl = (c == 0) ? bl1 : ((c == 1) ? bl2 : bl3);
    const int L = (c == 0) ? 16 : ((c == 1) ? 4 : 1);
    float hc[20];
#pragma unroll
    for (int l = 0; l < 20; ++l) hc[l] = h[l];
    for (int i = 0; i < L; ++i) {
      float o[20], t[20];
#pragma unroll
      for (int l = 0; l < 20; ++l) o[l] = hc[l];
      for (int j = 0; j < 3; ++j) {
        matvec20f(t, o, Wn + j * 400, bn + j * 20);
#pragma unroll
        for (int l = 0; l < 20; ++l) o[l] = swish_f(t[l]);
      }
      matvec20f(t, hc, Wl, bl);
#pragma unroll
      for (int l = 0; l < 20; ++l) hc[l] = o[l] + swish_f(t[l]);
      Wn += 1200; bn += 60; Wl += 400; bl += 20;
    }
#pragma unroll
    for (int l = 0; l < 20; ++l) acc[l] += hc[l];
  }
  float r[4];
#pragma unroll
  for (int j = 0; j < 4; ++j) r[j] = bb[j];
#pragma unroll
  for (int k = 0; k < 20; ++k)
#pragma unroll
    for (int j = 0; j < 4; ++j) r[j] = fmaf(acc[k], bW[k * 4 + j], r[j]);
  ((float4*)out)[tid] = make_float4(r[0], r[1], r[2], r[3]);
}

extern "C" void kernel_launch(void* const* d_in, const int* in_sizes, int n_in,
                              void* d_out, int out_size, void* d_ws, size_t ws_size,
                              hipStream_t stream) {
  int np = in_sizes[0] / 4;  // number of points

  if (ws_size >= (size_t)WS_NEED && (np % 32) == 0) {
    prep_kernel<<<N_MM, 64, 0, stream>>>(
        (const float*)d_in[1], (const float*)d_in[2], (const float*)d_in[3], (const float*)d_in[4],
        (const float*)d_in[5], (const float*)d_in[6], (const float*)d_in[7], (const float*)d_in[8],
        (const float*)d_in[9], (const float*)d_in[10], (const float*)d_in[11], (const float*)d_in[12],
        (const float*)d_in[13], (const float*)d_in[14], (const float*)d_in[15], (const float*)d_in[16],
        (u32*)d_ws);
    int ntiles = np / 32;
    int blocks = (ntiles + 3) / 4;
    reslinear_mfma<<<blocks, 256, 0, stream>>>(
        (const float*)d_in[0], (const uint4*)d_ws, (float*)d_out, ntiles);
  } else {
    reslinear_fallback<<<(np + 255) / 256, 256, 0, stream>>>(
        (const float*)d_in[0], (const float*)d_in[1], (const float*)d_in[2], (const float*)d_in[3],
        (const float*)d_in[4], (const float*)d_in[5], (const float*)d_in[6], (const float*)d_in[7],
        (const float*)d_in[8], (const float*)d_in[9], (const float*)d_in[10], (const float*)d_in[11],
        (const float*)d_in[12], (const float*)d_in[13], (const float*)d_in[14], (const float*)d_in[15],
        (const float*)d_in[16], (float*)d_out, np);
  }
}

// Round 7
// 726.503 us; speedup vs baseline: 2.7186x; 1.0215x over previous
//
#include <hip/hip_runtime.h>
#include <stdint.h>

typedef uint32_t u32;
typedef uint16_t u16;
typedef _Float16 f16;
typedef __attribute__((ext_vector_type(2))) _Float16 h2;
typedef __attribute__((ext_vector_type(8))) _Float16 f16v8;   // 8 f16 in 4 VGPRs
typedef __attribute__((ext_vector_type(16))) float f32x16;    // MFMA 32x32 accumulator

#define N_MM 86                 // front + 21 blocks * 4 + back
#define WS_NEED (N_MM * 2048)   // bytes: per matmul 2 frags * 64 lanes * 16B
#define LOG2E 1.44269504f
#define BETA (LOG2E / 4.5f)     // activation storage scale: m = BETA * v
#define INVBETA (4.5f / LOG2E)

// Packed-f16 coefficients for q(s), s=w^2, w=u/4.5: sigma2(u) ~= clamp01(0.5 + w*q(s)).
// Chebyshev interpolation of (sigma2-0.5)/w on u in [-4.5,4.5]; max err ~1.5e-4.
#define D0 0x3A3D3A3Du  //  0.77978
#define D1 0xB8FDB8FDu  // -0.62354
#define D2 0x38483848u  //  0.53516
#define D3 0xB539B539u  // -0.32642
#define D4 0x2DF12DF1u  //  0.092834
#define HALF2 0x38003800u
#define ONE2 0x3C003C00u
#define ONEF16 0x00003C00u

// ---------- packed helpers ----------
__device__ __forceinline__ u32 pkf16(float lo, float hi) {
  auto p = __builtin_amdgcn_cvt_pkrtz(lo, hi);  // v_cvt_pkrtz_f16_f32
  return __builtin_bit_cast(u32, p);
}
__device__ __forceinline__ h2 uph(u32 v) { return __builtin_bit_cast(h2, v); }
__device__ __forceinline__ u32 phu(h2 v) { return __builtin_bit_cast(u32, v); }
__device__ __forceinline__ u32 pkadd(u32 a, u32 b) { return phu(uph(a) + uph(b)); }

__device__ __forceinline__ f16v8 as_f16(uint4 v) { return __builtin_bit_cast(f16v8, v); }

__device__ __forceinline__ f32x16 zero16() {
  f32x16 z = {0.f, 0.f, 0.f, 0.f, 0.f, 0.f, 0.f, 0.f,
              0.f, 0.f, 0.f, 0.f, 0.f, 0.f, 0.f, 0.f};
  return z;
}

// packed polynomial swish: t = f32 pre-acts (w-domain x log2e... stored scale),
// out = packed m = c * sigma(c)
__device__ __forceinline__ void swish6(const f32x16& t, u32* o) {
  const h2 d0 = uph(D0), d1 = uph(D1), d2 = uph(D2), d3 = uph(D3), d4 = uph(D4);
  const h2 hf = uph(HALF2), zr = uph(0u), on = uph(ONE2);
#pragma unroll
  for (int i = 0; i < 6; ++i) {
    h2 c = uph(pkf16(t[2 * i], t[2 * i + 1]));
    h2 s = c * c;
    h2 p = __builtin_elementwise_fma(d4, s, d3);
    p = __builtin_elementwise_fma(p, s, d2);
    p = __builtin_elementwise_fma(p, s, d1);
    p = __builtin_elementwise_fma(p, s, d0);
    h2 sg = __builtin_elementwise_fma(c, p, hf);
    sg = __builtin_elementwise_max(sg, zr);
    sg = __builtin_elementwise_min(sg, on);
    o[i] = phu(c * sg);
  }
}

// matvec with preloaded A fragments (shared across tiles)
__device__ __forceinline__ f32x16 mm2(uint4 a0, uint4 a1, const u32* a6, const f32x16& Z) {
  uint4 b1, b2;
  b1.x = a6[0]; b1.y = a6[1]; b1.z = a6[2]; b1.w = a6[3];
  b2.x = a6[4]; b2.y = a6[5]; b2.z = ONEF16; b2.w = 0u;
  f32x16 acc = __builtin_amdgcn_mfma_f32_32x32x16_f16(as_f16(a0), as_f16(b1), Z, 0, 0, 0);
  acc = __builtin_amdgcn_mfma_f32_32x32x16_f16(as_f16(a1), as_f16(b2), acc, 0, 0, 0);
  return acc;
}

// ---------------- A-fragment prep: ws[mm][frag 0/1][lane][4 u32] ----------------
// Permuted logical-k mapping (s = 2r+hh is the in-lane slot):
//   blocks/back: f=0: k = 4g + s + (s>=4 ? 4 : 0)      (g=0: 0-3,8-11; g=1: 4-7,12-15)
//                f=1: g=0: s<4 -> 16+s, s==4 -> BIAS; else PAD
//   front:       f=0: g=0: s<4 -> k=s, s==4 -> BIAS; else PAD (single-MFMA matvec)
// m-domain scaling: hidden W x1, hidden b xBETA; front W,b xBETA; back W xINVBETA, b x1.
__device__ __forceinline__ u16 f16bits(float v) {
  f16 h = (f16)v;
  return __builtin_bit_cast(u16, h);
}

__global__ void prep_kernel(
    const float* __restrict__ fW, const float* __restrict__ fb,
    const float* __restrict__ bW, const float* __restrict__ bb,
    const float* __restrict__ Wn1, const float* __restrict__ bn1,
    const float* __restrict__ Wl1, const float* __restrict__ bl1,
    const float* __restrict__ Wn2, const float* __restrict__ bn2,
    const float* __restrict__ Wl2, const float* __restrict__ bl2,
    const float* __restrict__ Wn3, const float* __restrict__ bn3,
    const float* __restrict__ Wl3, const float* __restrict__ bl3,
    u32* __restrict__ ws) {
  int mm = blockIdx.x;     // 0..85
  int lane = threadIdx.x;  // 0..63
  int m = lane & 31, g = lane >> 5;
  const float *W, *B;
  int M, Kmax, Mmax;
  float sW, sB;
  bool front = (mm == 0);
  if (mm == 0) { W = fW; B = fb; M = 20; Kmax = 4; Mmax = 20; sW = BETA; sB = BETA; }
  else if (mm == 85) { W = bW; B = bb; M = 4; Kmax = 20; Mmax = 4; sW = INVBETA; sB = 1.0f; }
  else {
    int idx = mm - 1, bi = idx >> 2, j = idx & 3, lb;
    const float *Wn, *bn, *Wl, *bl;
    if (bi < 16)      { Wn = Wn1; bn = bn1; Wl = Wl1; bl = bl1; lb = bi; }
    else if (bi < 20) { Wn = Wn2; bn = bn2; Wl = Wl2; bl = bl2; lb = bi - 16; }
    else              { Wn = Wn3; bn = bn3; Wl = Wl3; bl = bl3; lb = 0; }
    if (j < 3) { W = Wn + (lb * 3 + j) * 400; B = bn + (lb * 3 + j) * 20; }
    else       { W = Wl + lb * 400;           B = bl + lb * 20; }
    M = 20; Kmax = 20; Mmax = 20; sW = 1.0f; sB = BETA;
  }
  for (int f = 0; f < 2; ++f) {
    for (int r = 0; r < 4; ++r) {
      u32 v = 0;
      for (int hh = 0; hh < 2; ++hh) {
        int s = 2 * r + hh;
        int k = -1;
        bool bias = false;
        if (front) {
          if (f == 0 && g == 0) {
            if (s < 4) k = s;
            else if (s == 4) bias = true;
          }
        } else {
          if (f == 0) k = 4 * g + s + (s >= 4 ? 4 : 0);
          else if (g == 0) {
            if (s < 4) k = 16 + s;
            else if (s == 4) bias = true;
          }
        }
        u32 e = 0;
        if (m < Mmax) {
          if (bias) e = f16bits(sB * B[m]);
          else if (k >= 0 && k < Kmax) e = f16bits(sW * W[k * M + m]);
        }
        v |= e << (16 * hh);
      }
      ws[mm * 512 + f * 256 + lane * 4 + r] = v;
    }
  }
}

// ---------------- main MFMA kernel: one wave = 64 points (2 x 32-tile, shared A) ----------------
__global__ __launch_bounds__(256) void reslinear_mfma(
    const float* __restrict__ x, const uint4* __restrict__ ws4,
    float* __restrict__ out, int ntiles2) {
  int lane = threadIdx.x & 63;
  int wave = threadIdx.x >> 6;
  int tile2 = blockIdx.x * 4 + wave;
  if (tile2 >= ntiles2) return;
  int n = lane & 31;
  bool hi = lane >= 32;
  int pt0 = tile2 * 64 + n;
  int pt1 = pt0 + 32;

  const f32x16 Z = zero16();  // persistent zero accumulator bank
  const uint4* __restrict__ wlane = ws4 + lane;

  // ---- front: c = BETA*(x @ fW + fb); shared A frag ----
  float4 x0 = ((const float4*)x)[pt0];
  float4 x1 = ((const float4*)x)[pt1];
  uint4 af = wlane[0];
  uint4 bfr0, bfr1;
  bfr0.x = pkf16(x0.x, x0.y); bfr0.y = pkf16(x0.z, x0.w); bfr0.z = ONEF16; bfr0.w = 0u;
  bfr1.x = pkf16(x1.x, x1.y); bfr1.y = pkf16(x1.z, x1.w); bfr1.z = ONEF16; bfr1.w = 0u;
  f32x16 hC0 = __builtin_amdgcn_mfma_f32_32x32x16_f16(as_f16(af), as_f16(bfr0), Z, 0, 0, 0);
  f32x16 hC1 = __builtin_amdgcn_mfma_f32_32x32x16_f16(as_f16(af), as_f16(bfr1), Z, 0, 0, 0);
  u32 h0[6], h1[6];
#pragma unroll
  for (int i = 0; i < 6; ++i) h0[i] = pkf16(hC0[2 * i], hC0[2 * i + 1]);
#pragma unroll
  for (int i = 0; i < 6; ++i) h1[i] = pkf16(hC1[2 * i], hC1[2 * i + 1]);

  u32 asum0[6], asum1[6];
#pragma unroll
  for (int i = 0; i < 6; ++i) { asum0[i] = 0u; asum1[i] = 0u; }

  const int CH_L[3] = {16, 4, 1};
  const int CH_B[3] = {0, 16, 20};

  for (int c = 0; c < 3; ++c) {
    u32 cur0[6], cur1[6];
#pragma unroll
    for (int i = 0; i < 6; ++i) { cur0[i] = h0[i]; cur1[i] = h1[i]; }
    int L = CH_L[c];
    const uint4* __restrict__ wp = wlane + (size_t)(1 + CH_B[c] * 4) * 128;
    for (int b = 0; b < L; ++b) {
      u32 o0[6], o1[6], p0[6], p1[6];
      uint4 a0, a1;

      a0 = wp[0]; a1 = wp[64]; wp += 128;      // matvec net.0
      f32x16 t0 = mm2(a0, a1, cur0, Z);
      f32x16 t1 = mm2(a0, a1, cur1, Z);
      swish6(t0, o0); swish6(t1, o1);

      a0 = wp[0]; a1 = wp[64]; wp += 128;      // matvec net.1
      t0 = mm2(a0, a1, o0, Z);
      t1 = mm2(a0, a1, o1, Z);
      swish6(t0, o0); swish6(t1, o1);

      a0 = wp[0]; a1 = wp[64]; wp += 128;      // matvec net.2
      t0 = mm2(a0, a1, o0, Z);
      t1 = mm2(a0, a1, o1, Z);
      swish6(t0, o0); swish6(t1, o1);

      a0 = wp[0]; a1 = wp[64]; wp += 128;      // lin shortcut from block input
      t0 = mm2(a0, a1, cur0, Z);
      t1 = mm2(a0, a1, cur1, Z);
      swish6(t0, p0); swish6(t1, p1);

#pragma unroll
      for (int i = 0; i < 6; ++i) { cur0[i] = pkadd(o0[i], p0[i]); cur1[i] = pkadd(o1[i], p1[i]); }
    }
#pragma unroll
    for (int i = 0; i < 6; ++i) { asum0[i] = pkadd(asum0[i], cur0[i]); asum1[i] = pkadd(asum1[i], cur1[i]); }
  }

  // ---- back: out = (bW/BETA) @ asum + bb (rows 0..3 of C, lo lanes) ----
  {
    uint4 a0 = wlane[85 * 128];
    uint4 a1 = wlane[85 * 128 + 64];
    f32x16 r0 = mm2(a0, a1, asum0, Z);
    f32x16 r1 = mm2(a0, a1, asum1, Z);
    if (!hi) {
      ((float4*)out)[pt0] = make_float4(r0[0], r0[1], r0[2], r0[3]);
      ((float4*)out)[pt1] = make_float4(r1[0], r1[1], r1[2], r1[3]);
    }
  }
}

// ---------------- fallback (ws too small / odd N): verified fp32 VALU path ----------------
__device__ __forceinline__ float fast_exp2(float x) {
#if __has_builtin(__builtin_amdgcn_exp2f)
  return __builtin_amdgcn_exp2f(x);
#else
  return exp2f(x);
#endif
}
__device__ __forceinline__ float fast_rcp(float x) {
#if __has_builtin(__builtin_amdgcn_rcpf)
  return __builtin_amdgcn_rcpf(x);
#else
  return 1.0f / x;
#endif
}
__device__ __forceinline__ float swish_f(float x) {
  float e = fast_exp2(x * -LOG2E);
  return x * fast_rcp(1.0f + e);
}
__device__ __forceinline__ void matvec20f(float* __restrict__ t, const float* __restrict__ o,
                                          const float* __restrict__ W, const float* __restrict__ b) {
#pragma unroll
  for (int l = 0; l < 20; ++l) t[l] = b[l];
#pragma unroll
  for (int k = 0; k < 20; ++k) {
    float ok = o[k];
#pragma unroll
    for (int l = 0; l < 20; ++l) t[l] = fmaf(ok, W[k * 20 + l], t[l]);
  }
}
__global__ __launch_bounds__(256) void reslinear_fallback(
    const float* __restrict__ x, const float* __restrict__ fW, const float* __restrict__ fb,
    const float* __restrict__ bW, const float* __restrict__ bb,
    const float* __restrict__ Wn1, const float* __restrict__ bn1, const float* __restrict__ Wl1, const float* __restrict__ bl1,
    const float* __restrict__ Wn2, const float* __restrict__ bn2, const float* __restrict__ Wl2, const float* __restrict__ bl2,
    const float* __restrict__ Wn3, const float* __restrict__ bn3, const float* __restrict__ Wl3, const float* __restrict__ bl3,
    float* __restrict__ out, int np) {
  int tid = blockIdx.x * 256 + threadIdx.x;
  if (tid >= np) return;
  float4 d = ((const float4*)x)[tid];
  float xv[4] = {d.x, d.y, d.z, d.w};
  float h[20];
#pragma unroll
  for (int l = 0; l < 20; ++l) h[l] = fb[l];
#pragma unroll
  for (int k = 0; k < 4; ++k)
#pragma unroll
    for (int l = 0; l < 20; ++l) h[l] = fmaf(xv[k], fW[k * 20 + l], h[l]);
  float acc[20];
#pragma unroll
  for (int l = 0; l < 20; ++l) acc[l] = 0.f;
  for (int c = 0; c < 3; ++c) {
    const float* Wn = (c == 0) ? Wn1 : ((c == 1) ? Wn2 : Wn3);
    const float* bn = (c == 0) ? bn1 : ((c == 1) ? bn2 : bn3);
    const float* Wl = (c == 0) ? Wl1 : ((c == 1) ? Wl2 : Wl3);
    const float* bl = (c == 0) ? bl1 : ((c == 1) ? bl2 : bl3);
    const int L = (c == 0) ? 16 : ((c == 1) ? 4 : 1);
    float hc[20];
#pragma unroll
    for (int l = 0; l < 20; ++l) hc[l] = h[l];
    for (int i = 0; i < L; ++i) {
      float o[20], t[20];
#pragma unroll
      for (int l = 0; l < 20; ++l) o[l] = hc[l];
      for (int j = 0; j < 3; ++j) {
        matvec20f(t, o, Wn + j * 400, bn + j * 20);
#pragma unroll
        for (int l = 0; l < 20; ++l) o[l] = swish_f(t[l]);
      }
      matvec20f(t, hc, Wl, bl);
#pragma unroll
      for (int l = 0; l < 20; ++l) hc[l] = o[l] + swish_f(t[l]);
      Wn += 1200; bn += 60; Wl += 400; bl += 20;
    }
#pragma unroll
    for (int l = 0; l < 20; ++l) acc[l] += hc[l];
  }
  float r[4];
#pragma unroll
  for (int j = 0; j < 4; ++j) r[j] = bb[j];
#pragma unroll
  for (int k = 0; k < 20; ++k)
#pragma unroll
    for (int j = 0; j < 4; ++j) r[j] = fmaf(acc[k], bW[k * 4 + j], r[j]);
  ((float4*)out)[tid] = make_float4(r[0], r[1], r[2], r[3]);
}

extern "C" void kernel_launch(void* const* d_in, const int* in_sizes, int n_in,
                              void* d_out, int out_size, void* d_ws, size_t ws_size,
                              hipStream_t stream) {
  int np = in_sizes[0] / 4;  // number of points

  if (ws_size >= (size_t)WS_NEED && (np % 64) == 0) {
    prep_kernel<<<N_MM, 64, 0, stream>>>(
        (const float*)d_in[1], (const float*)d_in[2], (const float*)d_in[3], (const float*)d_in[4],
        (const float*)d_in[5], (const float*)d_in[6], (const float*)d_in[7], (const float*)d_in[8],
        (const float*)d_in[9], (const float*)d_in[10], (const float*)d_in[11], (const float*)d_in[12],
        (const float*)d_in[13], (const float*)d_in[14], (const float*)d_in[15], (const float*)d_in[16],
        (u32*)d_ws);
    int ntiles2 = np / 64;
    int blocks = (ntiles2 + 3) / 4;
    reslinear_mfma<<<blocks, 256, 0, stream>>>(
        (const float*)d_in[0], (const uint4*)d_ws, (float*)d_out, ntiles2);
  } else {
    reslinear_fallback<<<(np + 255) / 256, 256, 0, stream>>>(
        (const float*)d_in[0], (const float*)d_in[1], (const float*)d_in[2], (const float*)d_in[3],
        (const float*)d_in[4], (const float*)d_in[5], (const float*)d_in[6], (const float*)d_in[7],
        (const float*)d_in[8], (const float*)d_in[9], (const float*)d_in[10], (const float*)d_in[11],
        (const float*)d_in[12], (const float*)d_in[13], (const float*)d_in[14], (const float*)d_in[15],
        (const float*)d_in[16], (float*)d_out, np);
  }
}